// Round 2
// baseline (1859.177 us; speedup 1.0000x reference)
//
#include <hip/hip_runtime.h>
#include <hip/hip_bf16.h>
#include <float.h>

#define N_FEAT 6272      // B*FH*FW = 8*28*28
#define C_DIM  1024
#define M_MEM  50000
#define M_PAD  50048     // 391 * 128
#define B_IMG  8
#define IMGSZ  224
#define NTILES_M 49      // 6272/128
#define NTILES_N 391     // 50048/128

typedef __attribute__((ext_vector_type(8))) short bf16x8;
typedef __attribute__((ext_vector_type(4))) float f32x4;

// ---------- helpers ----------

__device__ inline unsigned short f2bf(float x) {
  unsigned int u = __float_as_uint(x);
  u += 0x7FFFu + ((u >> 16) & 1u);
  return (unsigned short)(u >> 16);
}

__device__ inline void gload16(const unsigned short* g, unsigned short* l) {
  // async global->LDS, 16B per lane; LDS dest = wave-uniform base + lane*16
  __builtin_amdgcn_global_load_lds((const __attribute__((address_space(1))) void*)g,
                                   (__attribute__((address_space(3))) void*)l,
                                   16, 0, 0);
}

// ---------- 1. fp32 -> bf16 conversion + row sum-of-squares ----------
__global__ __launch_bounds__(256) void convert_rows_kernel(
    const float* __restrict__ src, unsigned short* __restrict__ dst,
    float* __restrict__ sq, unsigned int* __restrict__ minbits, int valid_rows)
{
  int row = blockIdx.x;
  int tid = threadIdx.x;
  float s = 0.f;
  ushort4 o = make_ushort4(0, 0, 0, 0);
  if (row < valid_rows) {
    const float4* s4 = (const float4*)(src + (size_t)row * C_DIM);
    float4 v = s4[tid];
    o.x = f2bf(v.x); o.y = f2bf(v.y); o.z = f2bf(v.z); o.w = f2bf(v.w);
    s = v.x * v.x + v.y * v.y + v.z * v.z + v.w * v.w;  // exact fp32 norms
  }
  ((ushort4*)(dst + (size_t)row * C_DIM))[tid] = o;

  #pragma unroll
  for (int off = 32; off > 0; off >>= 1) s += __shfl_down(s, off, 64);
  __shared__ float red[4];
  int lane = tid & 63, wave = tid >> 6;
  if (lane == 0) red[wave] = s;
  __syncthreads();
  if (tid == 0) {
    float t = red[0] + red[1] + red[2] + red[3];
    sq[row] = (row < valid_rows) ? t : FLT_MAX;
    if (minbits && row < valid_rows) minbits[row] = 0x7F7FFFFFu;  // FLT_MAX bits
  }
}

// ---------- 2. bf16 MFMA GEMM + row-min, 3-stage software pipeline ----------
// tile 128x128, BK=32, 4 waves (2x2 of 64x64). Three DISTINCT __shared__
// buffers (alias-analysis must see them as separate objects so the backend
// does not insert vmcnt(0) before ds_read while DMA to other buffers is in
// flight). Prefetch distance 2: tile k is consumed while k+1, k+2 stream.
__global__ __launch_bounds__(256) void gemm_min_kernel(
    const unsigned short* __restrict__ A,    // featB [6272][1024] bf16 bits
    const unsigned short* __restrict__ Bm,   // memB  [50048][1024] bf16 bits
    const float* __restrict__ f2, const float* __restrict__ m2,
    unsigned int* __restrict__ minbits)
{
  __shared__ unsigned short buf0[8192];   // 16 KB each: A[0..4095], B[4096..8191]
  __shared__ unsigned short buf1[8192];
  __shared__ unsigned short buf2[8192];

  const int tid  = threadIdx.x;
  const int wave = tid >> 6, lane = tid & 63;
  const int tileM = blockIdx.x, tileN = blockIdx.y;
  const int wr = wave >> 1, wc = wave & 1;
  const int quad = lane >> 4, r16 = lane & 15;

  f32x4 acc[4][4] = {};

  // staging chunk ids (16B chunks, c = q*128 + row): c0 = wave*128+lane, c1 = c0+64
  const int c0 = wave * 128 + lane;
  const int c1 = c0 + 64;
  const int r0 = c0 & 127, q0 = c0 >> 7;
  const int r1 = c1 & 127, q1 = c1 >> 7;

  const unsigned short* gA0 = A  + (size_t)(tileM * 128 + r0) * C_DIM + q0 * 8;
  const unsigned short* gA1 = A  + (size_t)(tileM * 128 + r1) * C_DIM + q1 * 8;
  const unsigned short* gB0 = Bm + (size_t)(tileN * 128 + r0) * C_DIM + q0 * 8;
  const unsigned short* gB1 = Bm + (size_t)(tileN * 128 + r1) * C_DIM + q1 * 8;

  // wave-uniform LDS staging offsets (shorts) within a buffer
  const int oA0 = wave * 1024;
  const int oA1 = oA0 + 512;
  const int oB0 = 4096 + wave * 1024;
  const int oB1 = oB0 + 512;

  const int abase = quad * 128 + wr * 64 + r16;
  const int bbase = quad * 128 + wc * 64 + r16;

#define ISSUE_TILE(BUF)                          \
  do {                                           \
    gload16(gA0, (BUF) + oA0);                   \
    gload16(gA1, (BUF) + oA1);                   \
    gload16(gB0, (BUF) + oB0);                   \
    gload16(gB1, (BUF) + oB1);                   \
    gA0 += 32; gA1 += 32; gB0 += 32; gB1 += 32;  \
  } while (0)

#define PIPE_STEP(RDBUF, WRBUF, DO_PRE, WAITSTR)                               \
  do {                                                                         \
    asm volatile("s_waitcnt " WAITSTR ::: "memory");                           \
    asm volatile("s_barrier" ::: "memory");                                    \
    const bf16x8* LA = (const bf16x8*)(RDBUF);                                 \
    const bf16x8* LB = (const bf16x8*)((RDBUF) + 4096);                        \
    bf16x8 a[4], b[4];                                                         \
    _Pragma("unroll") for (int t = 0; t < 4; ++t) a[t] = LA[abase + t * 16];   \
    _Pragma("unroll") for (int u = 0; u < 4; ++u) b[u] = LB[bbase + u * 16];   \
    if (DO_PRE) ISSUE_TILE(WRBUF);                                             \
    _Pragma("unroll") for (int t = 0; t < 4; ++t)                              \
      _Pragma("unroll") for (int u = 0; u < 4; ++u)                            \
        acc[t][u] = __builtin_amdgcn_mfma_f32_16x16x32_bf16(a[t], b[u],        \
                                                            acc[t][u], 0, 0, 0); \
  } while (0)

  // prologue: tiles 0,1 in flight
  ISSUE_TILE(buf0);
  ISSUE_TILE(buf1);

  // main: 30 iterations, hand-unrolled x3 so buffer selection is static.
  // At the top of iter k, outstanding = tiles k, k+1 (8 loads); vmcnt(4)
  // retires tile k's 4 while tile k+1 stays in flight.
  for (int kt = 0; kt < 30; kt += 3) {
    PIPE_STEP(buf0, buf2, true, "vmcnt(4)");
    PIPE_STEP(buf1, buf0, true, "vmcnt(4)");
    PIPE_STEP(buf2, buf1, true, "vmcnt(4)");
  }
  // peeled tail: tiles 30 (buf0) and 31 (buf1), no more prefetch
  PIPE_STEP(buf0, buf1, false, "vmcnt(4)");
  PIPE_STEP(buf1, buf0, false, "vmcnt(0)");

#undef PIPE_STEP
#undef ISSUE_TILE

  // epilogue: d2 = f2 + m2 - 2*dot, clamp >= 0, min over this block's 128 cols
  const int colbase = tileN * 128 + wc * 64 + r16;
  float m2v[4];
  #pragma unroll
  for (int u = 0; u < 4; ++u) m2v[u] = m2[colbase + u * 16];
  const int rowq = tileM * 128 + wr * 64 + quad * 4;
  #pragma unroll
  for (int t = 0; t < 4; ++t) {
    #pragma unroll
    for (int r = 0; r < 4; ++r) {
      int n = rowq + t * 16 + r;        // C/D layout: row = quad*4 + reg, col = r16
      float f2v = f2[n];
      float best = FLT_MAX;
      #pragma unroll
      for (int u = 0; u < 4; ++u) {
        float d = f2v + m2v[u] - 2.0f * acc[t][u][r];
        d = fmaxf(d, 0.0f);
        best = fminf(best, d);
      }
      best = fminf(best, __shfl_xor(best, 1, 64));
      best = fminf(best, __shfl_xor(best, 2, 64));
      best = fminf(best, __shfl_xor(best, 4, 64));
      best = fminf(best, __shfl_xor(best, 8, 64));
      if (r16 == 0) atomicMin(minbits + n, __float_as_uint(best));
    }
  }
}

// ---------- 3. sqrt + per-image max + 28x28 mask ----------
__global__ __launch_bounds__(256) void finalize_kernel(
    const unsigned int* __restrict__ minbits, float* __restrict__ m28,
    float* __restrict__ image_scores)
{
  int b = blockIdx.x, tid = threadIdx.x;
  float mx = 0.f;
  for (int i = tid; i < 784; i += 256) {
    float s = sqrtf(__uint_as_float(minbits[b * 784 + i]));
    m28[b * 784 + i] = s;
    mx = fmaxf(mx, s);
  }
  #pragma unroll
  for (int off = 32; off > 0; off >>= 1) mx = fmaxf(mx, __shfl_down(mx, off, 64));
  __shared__ float red[4];
  if ((tid & 63) == 0) red[tid >> 6] = mx;
  __syncthreads();
  if (tid == 0) image_scores[b] = fmaxf(fmaxf(red[0], red[1]), fmaxf(red[2], red[3]));
}

// ---------- 4. bilinear 28 -> 224 ----------
__global__ __launch_bounds__(256) void resize_kernel(
    const float* __restrict__ m28, float* __restrict__ out)
{
  int idx = blockIdx.x * 256 + threadIdx.x;
  if (idx >= B_IMG * IMGSZ * IMGSZ) return;
  int x = idx % IMGSZ, y = (idx / IMGSZ) % IMGSZ, b = idx / (IMGSZ * IMGSZ);
  float sy = (y + 0.5f) * 0.125f - 0.5f;
  float sx = (x + 0.5f) * 0.125f - 0.5f;
  int iy0 = (int)floorf(sy); float fy = sy - (float)iy0;
  int ix0 = (int)floorf(sx); float fx = sx - (float)ix0;
  int y0 = min(max(iy0, 0), 27), y1 = min(max(iy0 + 1, 0), 27);
  int x0 = min(max(ix0, 0), 27), x1 = min(max(ix0 + 1, 0), 27);
  const float* p = m28 + b * 784;
  float v00 = p[y0 * 28 + x0], v01 = p[y0 * 28 + x1];
  float v10 = p[y1 * 28 + x0], v11 = p[y1 * 28 + x1];
  out[idx] = (1.f - fy) * ((1.f - fx) * v00 + fx * v01) +
             fy         * ((1.f - fx) * v10 + fx * v11);
}

// ---------- 5. separable 17-tap gaussian, reflect padding ----------
__device__ inline void gauss17(float* g) {
  float s = 0.f;
  #pragma unroll
  for (int i = 0; i < 17; ++i) {
    float x = (float)(i - 8);
    g[i] = expf(-x * x * (1.0f / 32.0f));   // sigma=4 -> 2*sigma^2 = 32
    s += g[i];
  }
  float inv = 1.0f / s;
  #pragma unroll
  for (int i = 0; i < 17; ++i) g[i] *= inv;
}

__device__ inline int refl(int t) { return t < 0 ? -t : (t > 223 ? 446 - t : t); }

__global__ __launch_bounds__(256) void blur_h_kernel(
    const float* __restrict__ in, float* __restrict__ out)
{
  int idx = blockIdx.x * 256 + threadIdx.x;
  if (idx >= B_IMG * IMGSZ * IMGSZ) return;
  int x = idx % IMGSZ, y = (idx / IMGSZ) % IMGSZ, b = idx / (IMGSZ * IMGSZ);
  float g[17]; gauss17(g);
  const float* row = in + (size_t)b * IMGSZ * IMGSZ + y * IMGSZ;
  float s = 0.f;
  #pragma unroll
  for (int k = 0; k < 17; ++k) s += g[k] * row[refl(x + k - 8)];
  out[idx] = s;
}

__global__ __launch_bounds__(256) void blur_v_kernel(
    const float* __restrict__ in, float* __restrict__ out)
{
  int idx = blockIdx.x * 256 + threadIdx.x;
  if (idx >= B_IMG * IMGSZ * IMGSZ) return;
  int x = idx % IMGSZ, y = (idx / IMGSZ) % IMGSZ, b = idx / (IMGSZ * IMGSZ);
  float g[17]; gauss17(g);
  const float* img = in + (size_t)b * IMGSZ * IMGSZ;
  float s = 0.f;
  #pragma unroll
  for (int k = 0; k < 17; ++k) s += g[k] * img[refl(y + k - 8) * IMGSZ + x];
  out[idx] = s;
}

// ---------- launch ----------
extern "C" void kernel_launch(void* const* d_in, const int* in_sizes, int n_in,
                              void* d_out, int out_size, void* d_ws, size_t ws_size,
                              hipStream_t stream) {
  const float* features = (const float*)d_in[0];
  const float* memory   = (const float*)d_in[1];
  if (n_in >= 2 && in_sizes[0] > in_sizes[1]) {
    const float* t = features; features = memory; memory = t;
  }
  float* out = (float*)d_out;
  char* ws = (char*)d_ws;

  unsigned short* memB  = (unsigned short*)(ws);                        // 102,498,304 B
  unsigned short* featB = (unsigned short*)(ws + 102498304);            //  12,845,056 B
  float*        f2      = (float*)(ws + 115343360);
  float*        m2      = (float*)(ws + 115368448);
  unsigned int* minb    = (unsigned int*)(ws + 115568640);
  float*        m28     = (float*)(ws + 115593728);
  float*        rsz     = (float*)(ws + 115618816);
  float*        tmp     = (float*)(ws + 117224448);

  convert_rows_kernel<<<M_PAD, 256, 0, stream>>>(memory, memB, m2, nullptr, M_MEM);
  convert_rows_kernel<<<N_FEAT, 256, 0, stream>>>(features, featB, f2, minb, N_FEAT);

  dim3 grid(NTILES_M, NTILES_N);
  gemm_min_kernel<<<grid, 256, 0, stream>>>(featB, memB, f2, m2, minb);

  finalize_kernel<<<B_IMG, 256, 0, stream>>>(minb, m28, out);
  resize_kernel<<<(B_IMG * IMGSZ * IMGSZ) / 256, 256, 0, stream>>>(m28, rsz);
  blur_h_kernel<<<(B_IMG * IMGSZ * IMGSZ) / 256, 256, 0, stream>>>(rsz, tmp);
  blur_v_kernel<<<(B_IMG * IMGSZ * IMGSZ) / 256, 256, 0, stream>>>(tmp, out + 8);
}

// Round 3
// 1631.813 us; speedup vs baseline: 1.1393x; 1.1393x over previous
//
#include <hip/hip_runtime.h>
#include <hip/hip_bf16.h>
#include <float.h>

#define N_FEAT 6272      // B*FH*FW = 8*28*28
#define C_DIM  1024
#define M_MEM  50000
#define M_PAD  50048     // 391 * 128
#define B_IMG  8
#define IMGSZ  224
#define NTILES_M 49      // 6272/128
#define NTILES_N 391     // 50048/128
#define NTILES   19159   // 49*391
#define PER_XCD  2395    // ceil(19159/8)
#define GRID_PAD 19160   // 8*2395

typedef __attribute__((ext_vector_type(8))) short bf16x8;
typedef __attribute__((ext_vector_type(4))) float f32x4;

// ---------- helpers ----------

__device__ inline unsigned short f2bf(float x) {
  unsigned int u = __float_as_uint(x);
  u += 0x7FFFu + ((u >> 16) & 1u);
  return (unsigned short)(u >> 16);
}

__device__ inline void gload16(const unsigned short* g, unsigned short* l) {
  // async global->LDS, 16B per lane; LDS dest = wave-uniform base + lane*16
  __builtin_amdgcn_global_load_lds((const __attribute__((address_space(1))) void*)g,
                                   (__attribute__((address_space(3))) void*)l,
                                   16, 0, 0);
}

// ---------- 1. fp32 -> bf16 conversion + row sum-of-squares (1 wave / row) ----------
__global__ __launch_bounds__(256) void convert_rows_kernel(
    const float* __restrict__ src, unsigned short* __restrict__ dst,
    float* __restrict__ sq, unsigned int* __restrict__ minbits,
    int valid_rows, int total_rows)
{
  int row  = blockIdx.x * 4 + (threadIdx.x >> 6);
  int lane = threadIdx.x & 63;
  if (row >= total_rows) return;
  float s = 0.f;
  ushort4* d4 = (ushort4*)(dst + (size_t)row * C_DIM);
  if (row < valid_rows) {
    const float4* s4 = (const float4*)(src + (size_t)row * C_DIM);
    #pragma unroll
    for (int j = 0; j < 4; ++j) {
      float4 v = s4[lane + 64 * j];
      ushort4 o = make_ushort4(f2bf(v.x), f2bf(v.y), f2bf(v.z), f2bf(v.w));
      d4[lane + 64 * j] = o;
      s += v.x * v.x + v.y * v.y + v.z * v.z + v.w * v.w;  // exact fp32 norms
    }
  } else {
    ushort4 z = make_ushort4(0, 0, 0, 0);
    #pragma unroll
    for (int j = 0; j < 4; ++j) d4[lane + 64 * j] = z;
  }
  #pragma unroll
  for (int off = 32; off > 0; off >>= 1) s += __shfl_down(s, off, 64);
  if (lane == 0) {
    sq[row] = (row < valid_rows) ? s : FLT_MAX;   // pad rows never win the min
    if (minbits && row < valid_rows) minbits[row] = 0x7F7FFFFFu;  // FLT_MAX bits
  }
}

// ---------- 2. bf16 MFMA GEMM + row-min: BK=64, 4 blocks/CU, XCD swizzle ----------
// tile 128x128, BK=64 (16 K-iters -> half the barrier drains of BK=32).
// LDS 32KB single buffer; __launch_bounds__(256,4) caps regs at 128/wave ->
// 4 blocks/CU for latency hiding. Chunk layout c = q*128 + row (q = k-octet)
// keeps DMA lane order contiguous and fragment ds_read_b128 conflict-free.
__global__ __launch_bounds__(256, 4) void gemm_min_kernel(
    const unsigned short* __restrict__ A,    // featB [6272][1024] bf16 bits
    const unsigned short* __restrict__ Bm,   // memB  [50048][1024] bf16 bits
    const float* __restrict__ f2, const float* __restrict__ m2,
    unsigned int* __restrict__ minbits)
{
  __shared__ unsigned short lds[16384];  // 32 KB: A chunks [0..8191], B [8192..16383]

  // XCD swizzle: dispatch is assumed round-robin over 8 XCDs by linear id.
  // Each XCD gets a contiguous band of tiles, tileM-fast -> its 49-block runs
  // share one B tile (256KB) in that XCD's private L2.
  const int lid = blockIdx.x;
  const int t = (lid & 7) * PER_XCD + (lid >> 3);
  if (t >= NTILES) return;
  const int tileN = t / NTILES_M;
  const int tileM = t - tileN * NTILES_M;

  const int tid  = threadIdx.x;
  const int wave = tid >> 6, lane = tid & 63;
  const int wr = wave >> 1, wc = wave & 1;        // 2x2 wave grid, 64x64 each
  const int quad = lane >> 4, r16 = lane & 15;

  f32x4 acc[4][4] = {};

  // staging: 1024 16B-chunks per operand per iter; 4 issues per wave each.
  // chunk c = wave*256 + i*64 + lane; row = c&127, q = c>>7 (k-octet 0..7)
  const unsigned short* gA = A  + (size_t)tileM * 128 * C_DIM;  // wave-uniform -> SGPR base
  const unsigned short* gB = Bm + (size_t)tileN * 128 * C_DIM;
  int offG[4];
  #pragma unroll
  for (int i = 0; i < 4; ++i) {
    int c = wave * 256 + i * 64 + lane;
    offG[i] = (c & 127) * C_DIM + (c >> 7) * 8;   // shorts
  }
  const int ldsOff = wave * 2048;                  // shorts; + i*512 per issue

  for (int kt = 0; kt < 16; ++kt) {
    __syncthreads();                   // prev compute done before overwrite
    const int kbase = kt * 64;
    #pragma unroll
    for (int i = 0; i < 4; ++i) {
      gload16(gA + offG[i] + kbase, lds + ldsOff + i * 512);
      gload16(gB + offG[i] + kbase, lds + 8192 + ldsOff + i * 512);
    }
    __syncthreads();                   // drains DMA -> LDS valid

    const bf16x8* LA = (const bf16x8*)lds;
    const bf16x8* LB = (const bf16x8*)(lds + 8192);
    #pragma unroll
    for (int s = 0; s < 2; ++s) {      // two 16x16x32 k-steps per BK=64 tile
      const int ab = (s * 4 + quad) * 128 + wr * 64 + r16;
      const int bb = (s * 4 + quad) * 128 + wc * 64 + r16;
      bf16x8 a[4], b[4];
      #pragma unroll
      for (int i = 0; i < 4; ++i) a[i] = LA[ab + i * 16];
      #pragma unroll
      for (int j = 0; j < 4; ++j) b[j] = LB[bb + j * 16];
      #pragma unroll
      for (int i = 0; i < 4; ++i)
        #pragma unroll
        for (int j = 0; j < 4; ++j)
          acc[i][j] = __builtin_amdgcn_mfma_f32_16x16x32_bf16(a[i], b[j], acc[i][j], 0, 0, 0);
    }
  }

  // epilogue: d2 = f2 + m2 - 2*dot, clamp >= 0, min over this block's 128 cols
  const int colbase = tileN * 128 + wc * 64 + r16;
  float m2v[4];
  #pragma unroll
  for (int u = 0; u < 4; ++u) m2v[u] = m2[colbase + u * 16];
  const int rowq = tileM * 128 + wr * 64 + quad * 4;
  #pragma unroll
  for (int i = 0; i < 4; ++i) {
    #pragma unroll
    for (int r = 0; r < 4; ++r) {
      int n = rowq + i * 16 + r;        // C/D layout: row = quad*4 + reg, col = r16
      float f2v = f2[n];
      float best = FLT_MAX;
      #pragma unroll
      for (int u = 0; u < 4; ++u) {
        float d = f2v + m2v[u] - 2.0f * acc[i][u][r];
        d = fmaxf(d, 0.0f);             // clamp-then-min == max(min,0)
        best = fminf(best, d);
      }
      best = fminf(best, __shfl_xor(best, 1, 64));
      best = fminf(best, __shfl_xor(best, 2, 64));
      best = fminf(best, __shfl_xor(best, 4, 64));
      best = fminf(best, __shfl_xor(best, 8, 64));
      if (r16 == 0) atomicMin(minbits + n, __float_as_uint(best));
    }
  }
}

// ---------- 3. sqrt + per-image max + 28x28 mask ----------
__global__ __launch_bounds__(256) void finalize_kernel(
    const unsigned int* __restrict__ minbits, float* __restrict__ m28,
    float* __restrict__ image_scores)
{
  int b = blockIdx.x, tid = threadIdx.x;
  float mx = 0.f;
  for (int i = tid; i < 784; i += 256) {
    float s = sqrtf(__uint_as_float(minbits[b * 784 + i]));
    m28[b * 784 + i] = s;
    mx = fmaxf(mx, s);
  }
  #pragma unroll
  for (int off = 32; off > 0; off >>= 1) mx = fmaxf(mx, __shfl_down(mx, off, 64));
  __shared__ float red[4];
  if ((tid & 63) == 0) red[tid >> 6] = mx;
  __syncthreads();
  if (tid == 0) image_scores[b] = fmaxf(fmaxf(red[0], red[1]), fmaxf(red[2], red[3]));
}

// ---------- 4. bilinear 28 -> 224 ----------
__global__ __launch_bounds__(256) void resize_kernel(
    const float* __restrict__ m28, float* __restrict__ out)
{
  int idx = blockIdx.x * 256 + threadIdx.x;
  if (idx >= B_IMG * IMGSZ * IMGSZ) return;
  int x = idx % IMGSZ, y = (idx / IMGSZ) % IMGSZ, b = idx / (IMGSZ * IMGSZ);
  float sy = (y + 0.5f) * 0.125f - 0.5f;
  float sx = (x + 0.5f) * 0.125f - 0.5f;
  int iy0 = (int)floorf(sy); float fy = sy - (float)iy0;
  int ix0 = (int)floorf(sx); float fx = sx - (float)ix0;
  int y0 = min(max(iy0, 0), 27), y1 = min(max(iy0 + 1, 0), 27);
  int x0 = min(max(ix0, 0), 27), x1 = min(max(ix0 + 1, 0), 27);
  const float* p = m28 + b * 784;
  float v00 = p[y0 * 28 + x0], v01 = p[y0 * 28 + x1];
  float v10 = p[y1 * 28 + x0], v11 = p[y1 * 28 + x1];
  out[idx] = (1.f - fy) * ((1.f - fx) * v00 + fx * v01) +
             fy         * ((1.f - fx) * v10 + fx * v11);
}

// ---------- 5. separable 17-tap gaussian, reflect padding ----------
__device__ inline void gauss17(float* g) {
  float s = 0.f;
  #pragma unroll
  for (int i = 0; i < 17; ++i) {
    float x = (float)(i - 8);
    g[i] = expf(-x * x * (1.0f / 32.0f));   // sigma=4 -> 2*sigma^2 = 32
    s += g[i];
  }
  float inv = 1.0f / s;
  #pragma unroll
  for (int i = 0; i < 17; ++i) g[i] *= inv;
}

__device__ inline int refl(int t) { return t < 0 ? -t : (t > 223 ? 446 - t : t); }

__global__ __launch_bounds__(256) void blur_h_kernel(
    const float* __restrict__ in, float* __restrict__ out)
{
  int idx = blockIdx.x * 256 + threadIdx.x;
  if (idx >= B_IMG * IMGSZ * IMGSZ) return;
  int x = idx % IMGSZ, y = (idx / IMGSZ) % IMGSZ, b = idx / (IMGSZ * IMGSZ);
  float g[17]; gauss17(g);
  const float* row = in + (size_t)b * IMGSZ * IMGSZ + y * IMGSZ;
  float s = 0.f;
  #pragma unroll
  for (int k = 0; k < 17; ++k) s += g[k] * row[refl(x + k - 8)];
  out[idx] = s;
}

__global__ __launch_bounds__(256) void blur_v_kernel(
    const float* __restrict__ in, float* __restrict__ out)
{
  int idx = blockIdx.x * 256 + threadIdx.x;
  if (idx >= B_IMG * IMGSZ * IMGSZ) return;
  int x = idx % IMGSZ, y = (idx / IMGSZ) % IMGSZ, b = idx / (IMGSZ * IMGSZ);
  float g[17]; gauss17(g);
  const float* img = in + (size_t)b * IMGSZ * IMGSZ;
  float s = 0.f;
  #pragma unroll
  for (int k = 0; k < 17; ++k) s += g[k] * img[refl(y + k - 8) * IMGSZ + x];
  out[idx] = s;
}

// ---------- launch ----------
extern "C" void kernel_launch(void* const* d_in, const int* in_sizes, int n_in,
                              void* d_out, int out_size, void* d_ws, size_t ws_size,
                              hipStream_t stream) {
  const float* features = (const float*)d_in[0];
  const float* memory   = (const float*)d_in[1];
  if (n_in >= 2 && in_sizes[0] > in_sizes[1]) {
    const float* t = features; features = memory; memory = t;
  }
  float* out = (float*)d_out;
  char* ws = (char*)d_ws;

  unsigned short* memB  = (unsigned short*)(ws);                        // 102,498,304 B
  unsigned short* featB = (unsigned short*)(ws + 102498304);            //  12,845,056 B
  float*        f2      = (float*)(ws + 115343360);
  float*        m2      = (float*)(ws + 115368448);
  unsigned int* minb    = (unsigned int*)(ws + 115568640);
  float*        m28     = (float*)(ws + 115593728);
  float*        rsz     = (float*)(ws + 115618816);
  float*        tmp     = (float*)(ws + 117224448);

  convert_rows_kernel<<<M_PAD / 4, 256, 0, stream>>>(memory, memB, m2, nullptr, M_MEM, M_PAD);
  convert_rows_kernel<<<N_FEAT / 4, 256, 0, stream>>>(features, featB, f2, minb, N_FEAT, N_FEAT);

  gemm_min_kernel<<<GRID_PAD, 256, 0, stream>>>(featB, memB, f2, m2, minb);

  finalize_kernel<<<B_IMG, 256, 0, stream>>>(minb, m28, out);
  resize_kernel<<<(B_IMG * IMGSZ * IMGSZ) / 256, 256, 0, stream>>>(m28, rsz);
  blur_h_kernel<<<(B_IMG * IMGSZ * IMGSZ) / 256, 256, 0, stream>>>(rsz, tmp);
  blur_v_kernel<<<(B_IMG * IMGSZ * IMGSZ) / 256, 256, 0, stream>>>(tmp, out + 8);
}

// Round 4
// 1169.539 us; speedup vs baseline: 1.5897x; 1.3953x over previous
//
#include <hip/hip_runtime.h>
#include <hip/hip_bf16.h>
#include <float.h>

#define N_FEAT 6272      // B*FH*FW = 8*28*28
#define C_DIM  1024
#define M_MEM  50000
#define M_PAD  50048     // 391 * 128
#define B_IMG  8
#define IMGSZ  224
#define NTILES_M 49      // 6272/128
#define NTILES_N 391     // 50048/128
#define NTILES   19159   // 49*391
#define PER_XCD  2395    // ceil(19159/8)
#define GRID_PAD 19160   // 8*2395

typedef __attribute__((ext_vector_type(8))) short bf16x8;
typedef __attribute__((ext_vector_type(4))) float f32x4;

// ---------- helpers ----------

__device__ inline unsigned short f2bf(float x) {
  unsigned int u = __float_as_uint(x);
  u += 0x7FFFu + ((u >> 16) & 1u);
  return (unsigned short)(u >> 16);
}

// ---------- 1. fp32 -> bf16 conversion + row sum-of-squares (1 wave / row) ----------
__global__ __launch_bounds__(256) void convert_rows_kernel(
    const float* __restrict__ src, unsigned short* __restrict__ dst,
    float* __restrict__ sq, unsigned int* __restrict__ minbits,
    int valid_rows, int total_rows)
{
  int row  = blockIdx.x * 4 + (threadIdx.x >> 6);
  int lane = threadIdx.x & 63;
  if (row >= total_rows) return;
  float s = 0.f;
  ushort4* d4 = (ushort4*)(dst + (size_t)row * C_DIM);
  if (row < valid_rows) {
    const float4* s4 = (const float4*)(src + (size_t)row * C_DIM);
    #pragma unroll
    for (int j = 0; j < 4; ++j) {
      float4 v = s4[lane + 64 * j];
      ushort4 o = make_ushort4(f2bf(v.x), f2bf(v.y), f2bf(v.z), f2bf(v.w));
      d4[lane + 64 * j] = o;
      s += v.x * v.x + v.y * v.y + v.z * v.z + v.w * v.w;  // exact fp32 norms
    }
  } else {
    ushort4 z = make_ushort4(0, 0, 0, 0);
    #pragma unroll
    for (int j = 0; j < 4; ++j) d4[lane + 64 * j] = z;
  }
  #pragma unroll
  for (int off = 32; off > 0; off >>= 1) s += __shfl_down(s, off, 64);
  if (lane == 0) {
    sq[row] = (row < valid_rows) ? s : FLT_MAX;   // pad rows never win the min
    if (minbits && row < valid_rows) minbits[row] = 0x7F7FFFFFu;  // FLT_MAX bits
  }
}

// ---------- 2. bf16 MFMA GEMM + row-min: reg-prefetch double-buffer ----------
// tile 128x128, BK=32, 4 waves (2x2 of 64x64). CK-style pipeline:
//   regs hold tile k+1 (global_load in flight ACROSS barriers - reg dest, so
//   __syncthreads only drains lgkmcnt), LDS buf[p] holds tile k.
//   step: ds_read frags -> MFMA -> barrier -> ds_write regs -> load k+2 -> barrier.
// LDS chunk layout: chunk = q*128 + (row ^ (q<<2)), q = k-octet. Global loads
// are row-major coalesced (16 rows x 64B per instr); both ds_write_b128 and
// fragment ds_read_b128 land 2-way per bank (free).
__global__ __launch_bounds__(256, 3) void gemm_min_kernel(
    const unsigned short* __restrict__ A,    // featB [6272][1024] bf16 bits
    const unsigned short* __restrict__ Bm,   // memB  [50048][1024] bf16 bits
    const float* __restrict__ f2, const float* __restrict__ m2,
    unsigned int* __restrict__ minbits)
{
  __shared__ unsigned short lA[2][4096];   // 8 KB per buffer per operand
  __shared__ unsigned short lB[2][4096];

  // XCD swizzle: each XCD walks a contiguous tile band, tileM-fast
  const int lid = blockIdx.x;
  const int t = (lid & 7) * PER_XCD + (lid >> 3);
  if (t >= NTILES) return;
  const int tileN = t / NTILES_M;
  const int tileM = t - tileN * NTILES_M;

  const int tid  = threadIdx.x;
  const int wave = tid >> 6, lane = tid & 63;
  const int wr = wave >> 1, wc = wave & 1;        // 2x2 wave grid, 64x64 each
  const int quad = lane >> 4, r16 = lane & 15;

  f32x4 acc[4][4] = {};

  // staging thread mapping: q = k-octet slot (0..3), rows rowS and rowS+64
  const int q    = tid & 3;
  const int rowS = tid >> 2;
  const unsigned short* gA = A  + (size_t)(tileM * 128 + rowS) * C_DIM + q * 8;
  const unsigned short* gB = Bm + (size_t)(tileN * 128 + rowS) * C_DIM + q * 8;
  const int g1 = 64 * C_DIM;                       // +64 rows, in shorts
  const int wOff0 = (q * 128 + (rowS        ^ (q << 2))) * 8;   // shorts
  const int wOff1 = (q * 128 + ((rowS + 64) ^ (q << 2))) * 8;

  // fragment chunk indices (bf16x8 units)
  const int aidx = quad * 128 + wr * 64 + (r16 ^ (quad << 2));
  const int bidx = quad * 128 + wc * 64 + (r16 ^ (quad << 2));

  int4 pA0, pA1, pB0, pB1;

  // prologue: tile 0 -> regs -> lds[0]; tile 1 -> regs; one-time drain
  pA0 = *(const int4*)(gA);
  pA1 = *(const int4*)(gA + g1);
  pB0 = *(const int4*)(gB);
  pB1 = *(const int4*)(gB + g1);
  *(int4*)(&lA[0][wOff0]) = pA0;
  *(int4*)(&lA[0][wOff1]) = pA1;
  *(int4*)(&lB[0][wOff0]) = pB0;
  *(int4*)(&lB[0][wOff1]) = pB1;
  pA0 = *(const int4*)(gA + 32);
  pA1 = *(const int4*)(gA + g1 + 32);
  pB0 = *(const int4*)(gB + 32);
  pB1 = *(const int4*)(gB + g1 + 32);
  __syncthreads();

  auto step = [&](int pbuf, int kt, bool doLoad) {
    const bf16x8* LA_ = (const bf16x8*)lA[pbuf];
    const bf16x8* LB_ = (const bf16x8*)lB[pbuf];
    bf16x8 a[4], b[4];
    #pragma unroll
    for (int i = 0; i < 4; ++i) a[i] = LA_[aidx + i * 16];
    #pragma unroll
    for (int j = 0; j < 4; ++j) b[j] = LB_[bidx + j * 16];
    #pragma unroll
    for (int i = 0; i < 4; ++i)
      #pragma unroll
      for (int j = 0; j < 4; ++j)
        acc[i][j] = __builtin_amdgcn_mfma_f32_16x16x32_bf16(a[i], b[j], acc[i][j], 0, 0, 0);
    __syncthreads();                 // waves done reading buf[pbuf^1] (iter kt-1)
    unsigned short* wA = lA[pbuf ^ 1];
    unsigned short* wB = lB[pbuf ^ 1];
    *(int4*)(wA + wOff0) = pA0;      // tile kt+1 regs -> LDS
    *(int4*)(wA + wOff1) = pA1;
    *(int4*)(wB + wOff0) = pB0;
    *(int4*)(wB + wOff1) = pB1;
    if (doLoad) {                    // issue tile kt+2; stays in flight past barrier
      const int o = (kt + 2) * 32;
      pA0 = *(const int4*)(gA + o);
      pA1 = *(const int4*)(gA + g1 + o);
      pB0 = *(const int4*)(gB + o);
      pB1 = *(const int4*)(gB + g1 + o);
    }
    __syncthreads();                 // tile kt+1 writes visible (lgkmcnt only)
  };

  for (int kt = 0; kt < 30; kt += 2) {
    step(0, kt, true);
    step(1, kt + 1, true);
  }
  step(0, 30, false);
  step(1, 31, false);

  // epilogue: d2 = f2 + m2 - 2*dot, clamp >= 0, min over this block's 128 cols
  const int colbase = tileN * 128 + wc * 64 + r16;
  float m2v[4];
  #pragma unroll
  for (int u = 0; u < 4; ++u) m2v[u] = m2[colbase + u * 16];
  const int rowq = tileM * 128 + wr * 64 + quad * 4;
  #pragma unroll
  for (int i = 0; i < 4; ++i) {
    #pragma unroll
    for (int r = 0; r < 4; ++r) {
      int n = rowq + i * 16 + r;        // C/D layout: row = quad*4 + reg, col = r16
      float f2v = f2[n];
      float best = FLT_MAX;
      #pragma unroll
      for (int u = 0; u < 4; ++u) {
        float d = f2v + m2v[u] - 2.0f * acc[i][u][r];
        d = fmaxf(d, 0.0f);             // clamp-then-min == max(min,0)
        best = fminf(best, d);
      }
      best = fminf(best, __shfl_xor(best, 1, 64));
      best = fminf(best, __shfl_xor(best, 2, 64));
      best = fminf(best, __shfl_xor(best, 4, 64));
      best = fminf(best, __shfl_xor(best, 8, 64));
      if (r16 == 0) atomicMin(minbits + n, __float_as_uint(best));
    }
  }
}

// ---------- 3. sqrt + per-image max + 28x28 mask ----------
__global__ __launch_bounds__(256) void finalize_kernel(
    const unsigned int* __restrict__ minbits, float* __restrict__ m28,
    float* __restrict__ image_scores)
{
  int b = blockIdx.x, tid = threadIdx.x;
  float mx = 0.f;
  for (int i = tid; i < 784; i += 256) {
    float s = sqrtf(__uint_as_float(minbits[b * 784 + i]));
    m28[b * 784 + i] = s;
    mx = fmaxf(mx, s);
  }
  #pragma unroll
  for (int off = 32; off > 0; off >>= 1) mx = fmaxf(mx, __shfl_down(mx, off, 64));
  __shared__ float red[4];
  if ((tid & 63) == 0) red[tid >> 6] = mx;
  __syncthreads();
  if (tid == 0) image_scores[b] = fmaxf(fmaxf(red[0], red[1]), fmaxf(red[2], red[3]));
}

// ---------- 4. bilinear 28 -> 224 ----------
__global__ __launch_bounds__(256) void resize_kernel(
    const float* __restrict__ m28, float* __restrict__ out)
{
  int idx = blockIdx.x * 256 + threadIdx.x;
  if (idx >= B_IMG * IMGSZ * IMGSZ) return;
  int x = idx % IMGSZ, y = (idx / IMGSZ) % IMGSZ, b = idx / (IMGSZ * IMGSZ);
  float sy = (y + 0.5f) * 0.125f - 0.5f;
  float sx = (x + 0.5f) * 0.125f - 0.5f;
  int iy0 = (int)floorf(sy); float fy = sy - (float)iy0;
  int ix0 = (int)floorf(sx); float fx = sx - (float)ix0;
  int y0 = min(max(iy0, 0), 27), y1 = min(max(iy0 + 1, 0), 27);
  int x0 = min(max(ix0, 0), 27), x1 = min(max(ix0 + 1, 0), 27);
  const float* p = m28 + b * 784;
  float v00 = p[y0 * 28 + x0], v01 = p[y0 * 28 + x1];
  float v10 = p[y1 * 28 + x0], v11 = p[y1 * 28 + x1];
  out[idx] = (1.f - fy) * ((1.f - fx) * v00 + fx * v01) +
             fy         * ((1.f - fx) * v10 + fx * v11);
}

// ---------- 5. separable 17-tap gaussian, reflect padding ----------
__device__ inline void gauss17(float* g) {
  float s = 0.f;
  #pragma unroll
  for (int i = 0; i < 17; ++i) {
    float x = (float)(i - 8);
    g[i] = expf(-x * x * (1.0f / 32.0f));   // sigma=4 -> 2*sigma^2 = 32
    s += g[i];
  }
  float inv = 1.0f / s;
  #pragma unroll
  for (int i = 0; i < 17; ++i) g[i] *= inv;
}

__device__ inline int refl(int t) { return t < 0 ? -t : (t > 223 ? 446 - t : t); }

__global__ __launch_bounds__(256) void blur_h_kernel(
    const float* __restrict__ in, float* __restrict__ out)
{
  int idx = blockIdx.x * 256 + threadIdx.x;
  if (idx >= B_IMG * IMGSZ * IMGSZ) return;
  int x = idx % IMGSZ, y = (idx / IMGSZ) % IMGSZ, b = idx / (IMGSZ * IMGSZ);
  float g[17]; gauss17(g);
  const float* row = in + (size_t)b * IMGSZ * IMGSZ + y * IMGSZ;
  float s = 0.f;
  #pragma unroll
  for (int k = 0; k < 17; ++k) s += g[k] * row[refl(x + k - 8)];
  out[idx] = s;
}

__global__ __launch_bounds__(256) void blur_v_kernel(
    const float* __restrict__ in, float* __restrict__ out)
{
  int idx = blockIdx.x * 256 + threadIdx.x;
  if (idx >= B_IMG * IMGSZ * IMGSZ) return;
  int x = idx % IMGSZ, y = (idx / IMGSZ) % IMGSZ, b = idx / (IMGSZ * IMGSZ);
  float g[17]; gauss17(g);
  const float* img = in + (size_t)b * IMGSZ * IMGSZ;
  float s = 0.f;
  #pragma unroll
  for (int k = 0; k < 17; ++k) s += g[k] * img[refl(y + k - 8) * IMGSZ + x];
  out[idx] = s;
}

// ---------- launch ----------
extern "C" void kernel_launch(void* const* d_in, const int* in_sizes, int n_in,
                              void* d_out, int out_size, void* d_ws, size_t ws_size,
                              hipStream_t stream) {
  const float* features = (const float*)d_in[0];
  const float* memory   = (const float*)d_in[1];
  if (n_in >= 2 && in_sizes[0] > in_sizes[1]) {
    const float* t = features; features = memory; memory = t;
  }
  float* out = (float*)d_out;
  char* ws = (char*)d_ws;

  unsigned short* memB  = (unsigned short*)(ws);                        // 102,498,304 B
  unsigned short* featB = (unsigned short*)(ws + 102498304);            //  12,845,056 B
  float*        f2      = (float*)(ws + 115343360);
  float*        m2      = (float*)(ws + 115368448);
  unsigned int* minb    = (unsigned int*)(ws + 115568640);
  float*        m28     = (float*)(ws + 115593728);
  float*        rsz     = (float*)(ws + 115618816);
  float*        tmp     = (float*)(ws + 117224448);

  convert_rows_kernel<<<M_PAD / 4, 256, 0, stream>>>(memory, memB, m2, nullptr, M_MEM, M_PAD);
  convert_rows_kernel<<<N_FEAT / 4, 256, 0, stream>>>(features, featB, f2, minb, N_FEAT, N_FEAT);

  gemm_min_kernel<<<GRID_PAD, 256, 0, stream>>>(featB, memB, f2, m2, minb);

  finalize_kernel<<<B_IMG, 256, 0, stream>>>(minb, m28, out);
  resize_kernel<<<(B_IMG * IMGSZ * IMGSZ) / 256, 256, 0, stream>>>(m28, rsz);
  blur_h_kernel<<<(B_IMG * IMGSZ * IMGSZ) / 256, 256, 0, stream>>>(rsz, tmp);
  blur_v_kernel<<<(B_IMG * IMGSZ * IMGSZ) / 256, 256, 0, stream>>>(tmp, out + 8);
}

// Round 5
// 1129.653 us; speedup vs baseline: 1.6458x; 1.0353x over previous
//
#include <hip/hip_runtime.h>
#include <hip/hip_bf16.h>
#include <float.h>

#define N_FEAT 6272      // B*FH*FW = 8*28*28
#define C_DIM  1024
#define M_MEM  50000
#define M_PAD  50048     // 391 * 128
#define B_IMG  8
#define IMGSZ  224
#define NTILES_M 49      // 6272/128
#define NTILES_N 391     // 50048/128
#define NTILES   19159   // 49*391
#define PER_XCD  2395    // ceil(19159/8)
#define GRID_PAD 19160   // 8*2395

typedef __attribute__((ext_vector_type(8))) short bf16x8;
typedef __attribute__((ext_vector_type(4))) float f32x4;

// ---------- helpers ----------

__device__ inline unsigned short f2bf(float x) {
  unsigned int u = __float_as_uint(x);
  u += 0x7FFFu + ((u >> 16) & 1u);
  return (unsigned short)(u >> 16);
}

// ---------- 1. fp32 -> bf16 conversion + row sum-of-squares (1 wave / row) ----------
__global__ __launch_bounds__(256) void convert_rows_kernel(
    const float* __restrict__ src, unsigned short* __restrict__ dst,
    float* __restrict__ sq, unsigned int* __restrict__ minbits,
    int valid_rows, int total_rows)
{
  int row  = blockIdx.x * 4 + (threadIdx.x >> 6);
  int lane = threadIdx.x & 63;
  if (row >= total_rows) return;
  float s = 0.f;
  ushort4* d4 = (ushort4*)(dst + (size_t)row * C_DIM);
  if (row < valid_rows) {
    const float4* s4 = (const float4*)(src + (size_t)row * C_DIM);
    #pragma unroll
    for (int j = 0; j < 4; ++j) {
      float4 v = s4[lane + 64 * j];
      ushort4 o = make_ushort4(f2bf(v.x), f2bf(v.y), f2bf(v.z), f2bf(v.w));
      d4[lane + 64 * j] = o;
      s += v.x * v.x + v.y * v.y + v.z * v.z + v.w * v.w;  // exact fp32 norms
    }
  } else {
    ushort4 z = make_ushort4(0, 0, 0, 0);
    #pragma unroll
    for (int j = 0; j < 4; ++j) d4[lane + 64 * j] = z;
  }
  #pragma unroll
  for (int off = 32; off > 0; off >>= 1) s += __shfl_down(s, off, 64);
  if (lane == 0) {
    sq[row] = (row < valid_rows) ? s : FLT_MAX;   // pad rows never win the min
    if (minbits && row < valid_rows) minbits[row] = 0x7F7FFFFFu;  // FLT_MAX bits
  }
}

// ---------- 2. bf16 MFMA GEMM + row-min: reg-prefetch double-buffer ----------
// tile 128x128, BK=32, 4 waves (2x2 of 64x64). CK-style pipeline:
//   regs hold tile k+1 (global_load in flight ACROSS barriers - reg dest, so
//   __syncthreads only drains lgkmcnt), LDS buf[p] holds tile k.
// LDS chunk layout: chunk = q*128 + (row ^ (q<<1)), q = k-octet.
// b128 ops execute in 8-lane phases (8x16B = 128B/clk): write phase is
// (rowS in {2r,2r+1}) x (q 0..3) -> {2r,2r+1}^{0,2,4,6} = all 8 bank-groups;
// read phase is (quad fixed, 8 consecutive r16) ^ 2*quad = permutation.
// Both conflict-free (the R4 q<<2 variant collapsed writes onto 4 groups).
__global__ __launch_bounds__(256, 3) void gemm_min_kernel(
    const unsigned short* __restrict__ A,    // featB [6272][1024] bf16 bits
    const unsigned short* __restrict__ Bm,   // memB  [50048][1024] bf16 bits
    const float* __restrict__ f2, const float* __restrict__ m2,
    unsigned int* __restrict__ minbits)
{
  __shared__ unsigned short lA[2][4096];   // 8 KB per buffer per operand
  __shared__ unsigned short lB[2][4096];

  // XCD swizzle: each XCD walks a contiguous tile band, tileM-fast
  const int lid = blockIdx.x;
  const int t = (lid & 7) * PER_XCD + (lid >> 3);
  if (t >= NTILES) return;
  const int tileN = t / NTILES_M;
  const int tileM = t - tileN * NTILES_M;

  const int tid  = threadIdx.x;
  const int wave = tid >> 6, lane = tid & 63;
  const int wr = wave >> 1, wc = wave & 1;        // 2x2 wave grid, 64x64 each
  const int quad = lane >> 4, r16 = lane & 15;

  f32x4 acc[4][4] = {};

  // staging thread mapping: q = k-octet slot (0..3), rows rowS and rowS+64
  const int q    = tid & 3;
  const int rowS = tid >> 2;
  const unsigned short* gA = A  + (size_t)(tileM * 128 + rowS) * C_DIM + q * 8;
  const unsigned short* gB = Bm + (size_t)(tileN * 128 + rowS) * C_DIM + q * 8;
  const int g1 = 64 * C_DIM;                       // +64 rows, in shorts
  const int wOff0 = (q * 128 + (rowS        ^ (q << 1))) * 8;   // shorts
  const int wOff1 = (q * 128 + ((rowS + 64) ^ (q << 1))) * 8;

  // fragment chunk indices (bf16x8 units)
  const int aidx = quad * 128 + wr * 64 + (r16 ^ (quad << 1));
  const int bidx = quad * 128 + wc * 64 + (r16 ^ (quad << 1));

  int4 pA0, pA1, pB0, pB1;

  // prologue: tile 0 -> regs -> lds[0]; tile 1 -> regs; one-time drain
  pA0 = *(const int4*)(gA);
  pA1 = *(const int4*)(gA + g1);
  pB0 = *(const int4*)(gB);
  pB1 = *(const int4*)(gB + g1);
  *(int4*)(&lA[0][wOff0]) = pA0;
  *(int4*)(&lA[0][wOff1]) = pA1;
  *(int4*)(&lB[0][wOff0]) = pB0;
  *(int4*)(&lB[0][wOff1]) = pB1;
  pA0 = *(const int4*)(gA + 32);
  pA1 = *(const int4*)(gA + g1 + 32);
  pB0 = *(const int4*)(gB + 32);
  pB1 = *(const int4*)(gB + g1 + 32);
  __syncthreads();

  auto step = [&](int pbuf, int kt, bool doLoad) {
    const bf16x8* LA_ = (const bf16x8*)lA[pbuf];
    const bf16x8* LB_ = (const bf16x8*)lB[pbuf];
    bf16x8 a[4], b[4];
    #pragma unroll
    for (int i = 0; i < 4; ++i) a[i] = LA_[aidx + i * 16];
    #pragma unroll
    for (int j = 0; j < 4; ++j) b[j] = LB_[bidx + j * 16];
    #pragma unroll
    for (int i = 0; i < 4; ++i)
      #pragma unroll
      for (int j = 0; j < 4; ++j)
        acc[i][j] = __builtin_amdgcn_mfma_f32_16x16x32_bf16(a[i], b[j], acc[i][j], 0, 0, 0);
    __syncthreads();                 // waves done reading buf[pbuf^1] (iter kt-1)
    unsigned short* wA = lA[pbuf ^ 1];
    unsigned short* wB = lB[pbuf ^ 1];
    *(int4*)(wA + wOff0) = pA0;      // tile kt+1 regs -> LDS
    *(int4*)(wA + wOff1) = pA1;
    *(int4*)(wB + wOff0) = pB0;
    *(int4*)(wB + wOff1) = pB1;
    if (doLoad) {                    // issue tile kt+2; stays in flight past barrier
      const int o = (kt + 2) * 32;
      pA0 = *(const int4*)(gA + o);
      pA1 = *(const int4*)(gA + g1 + o);
      pB0 = *(const int4*)(gB + o);
      pB1 = *(const int4*)(gB + g1 + o);
    }
    __syncthreads();                 // tile kt+1 writes visible (lgkmcnt only)
  };

  for (int kt = 0; kt < 30; kt += 2) {
    step(0, kt, true);
    step(1, kt + 1, true);
  }
  step(0, 30, false);
  step(1, 31, false);

  // epilogue: d2 = f2 + m2 - 2*dot, clamp >= 0, min over this block's 128 cols
  const int colbase = tileN * 128 + wc * 64 + r16;
  float m2v[4];
  #pragma unroll
  for (int u = 0; u < 4; ++u) m2v[u] = m2[colbase + u * 16];
  const int rowq = tileM * 128 + wr * 64 + quad * 4;
  #pragma unroll
  for (int i = 0; i < 4; ++i) {
    #pragma unroll
    for (int r = 0; r < 4; ++r) {
      int n = rowq + i * 16 + r;        // C/D layout: row = quad*4 + reg, col = r16
      float f2v = f2[n];
      float best = FLT_MAX;
      #pragma unroll
      for (int u = 0; u < 4; ++u) {
        float d = f2v + m2v[u] - 2.0f * acc[i][u][r];
        d = fmaxf(d, 0.0f);             // clamp-then-min == max(min,0)
        best = fminf(best, d);
      }
      best = fminf(best, __shfl_xor(best, 1, 64));
      best = fminf(best, __shfl_xor(best, 2, 64));
      best = fminf(best, __shfl_xor(best, 4, 64));
      best = fminf(best, __shfl_xor(best, 8, 64));
      if (r16 == 0) atomicMin(minbits + n, __float_as_uint(best));
    }
  }
}

// ---------- 3. sqrt + per-image max + 28x28 mask ----------
__global__ __launch_bounds__(256) void finalize_kernel(
    const unsigned int* __restrict__ minbits, float* __restrict__ m28,
    float* __restrict__ image_scores)
{
  int b = blockIdx.x, tid = threadIdx.x;
  float mx = 0.f;
  for (int i = tid; i < 784; i += 256) {
    float s = sqrtf(__uint_as_float(minbits[b * 784 + i]));
    m28[b * 784 + i] = s;
    mx = fmaxf(mx, s);
  }
  #pragma unroll
  for (int off = 32; off > 0; off >>= 1) mx = fmaxf(mx, __shfl_down(mx, off, 64));
  __shared__ float red[4];
  if ((tid & 63) == 0) red[tid >> 6] = mx;
  __syncthreads();
  if (tid == 0) image_scores[b] = fmaxf(fmaxf(red[0], red[1]), fmaxf(red[2], red[3]));
}

// ---------- 4. bilinear 28 -> 224 ----------
__global__ __launch_bounds__(256) void resize_kernel(
    const float* __restrict__ m28, float* __restrict__ out)
{
  int idx = blockIdx.x * 256 + threadIdx.x;
  if (idx >= B_IMG * IMGSZ * IMGSZ) return;
  int x = idx % IMGSZ, y = (idx / IMGSZ) % IMGSZ, b = idx / (IMGSZ * IMGSZ);
  float sy = (y + 0.5f) * 0.125f - 0.5f;
  float sx = (x + 0.5f) * 0.125f - 0.5f;
  int iy0 = (int)floorf(sy); float fy = sy - (float)iy0;
  int ix0 = (int)floorf(sx); float fx = sx - (float)ix0;
  int y0 = min(max(iy0, 0), 27), y1 = min(max(iy0 + 1, 0), 27);
  int x0 = min(max(ix0, 0), 27), x1 = min(max(ix0 + 1, 0), 27);
  const float* p = m28 + b * 784;
  float v00 = p[y0 * 28 + x0], v01 = p[y0 * 28 + x1];
  float v10 = p[y1 * 28 + x0], v11 = p[y1 * 28 + x1];
  out[idx] = (1.f - fy) * ((1.f - fx) * v00 + fx * v01) +
             fy         * ((1.f - fx) * v10 + fx * v11);
}

// ---------- 5. separable 17-tap gaussian, reflect padding ----------
__device__ inline void gauss17(float* g) {
  float s = 0.f;
  #pragma unroll
  for (int i = 0; i < 17; ++i) {
    float x = (float)(i - 8);
    g[i] = expf(-x * x * (1.0f / 32.0f));   // sigma=4 -> 2*sigma^2 = 32
    s += g[i];
  }
  float inv = 1.0f / s;
  #pragma unroll
  for (int i = 0; i < 17; ++i) g[i] *= inv;
}

__device__ inline int refl(int t) { return t < 0 ? -t : (t > 223 ? 446 - t : t); }

__global__ __launch_bounds__(256) void blur_h_kernel(
    const float* __restrict__ in, float* __restrict__ out)
{
  int idx = blockIdx.x * 256 + threadIdx.x;
  if (idx >= B_IMG * IMGSZ * IMGSZ) return;
  int x = idx % IMGSZ, y = (idx / IMGSZ) % IMGSZ, b = idx / (IMGSZ * IMGSZ);
  float g[17]; gauss17(g);
  const float* row = in + (size_t)b * IMGSZ * IMGSZ + y * IMGSZ;
  float s = 0.f;
  #pragma unroll
  for (int k = 0; k < 17; ++k) s += g[k] * row[refl(x + k - 8)];
  out[idx] = s;
}

__global__ __launch_bounds__(256) void blur_v_kernel(
    const float* __restrict__ in, float* __restrict__ out)
{
  int idx = blockIdx.x * 256 + threadIdx.x;
  if (idx >= B_IMG * IMGSZ * IMGSZ) return;
  int x = idx % IMGSZ, y = (idx / IMGSZ) % IMGSZ, b = idx / (IMGSZ * IMGSZ);
  float g[17]; gauss17(g);
  const float* img = in + (size_t)b * IMGSZ * IMGSZ;
  float s = 0.f;
  #pragma unroll
  for (int k = 0; k < 17; ++k) s += g[k] * img[refl(y + k - 8) * IMGSZ + x];
  out[idx] = s;
}

// ---------- launch ----------
extern "C" void kernel_launch(void* const* d_in, const int* in_sizes, int n_in,
                              void* d_out, int out_size, void* d_ws, size_t ws_size,
                              hipStream_t stream) {
  const float* features = (const float*)d_in[0];
  const float* memory   = (const float*)d_in[1];
  if (n_in >= 2 && in_sizes[0] > in_sizes[1]) {
    const float* t = features; features = memory; memory = t;
  }
  float* out = (float*)d_out;
  char* ws = (char*)d_ws;

  unsigned short* memB  = (unsigned short*)(ws);                        // 102,498,304 B
  unsigned short* featB = (unsigned short*)(ws + 102498304);            //  12,845,056 B
  float*        f2      = (float*)(ws + 115343360);
  float*        m2      = (float*)(ws + 115368448);
  unsigned int* minb    = (unsigned int*)(ws + 115568640);
  float*        m28     = (float*)(ws + 115593728);
  float*        rsz     = (float*)(ws + 115618816);
  float*        tmp     = (float*)(ws + 117224448);

  convert_rows_kernel<<<M_PAD / 4, 256, 0, stream>>>(memory, memB, m2, nullptr, M_MEM, M_PAD);
  convert_rows_kernel<<<N_FEAT / 4, 256, 0, stream>>>(features, featB, f2, minb, N_FEAT, N_FEAT);

  gemm_min_kernel<<<GRID_PAD, 256, 0, stream>>>(featB, memB, f2, m2, minb);

  finalize_kernel<<<B_IMG, 256, 0, stream>>>(minb, m28, out);
  resize_kernel<<<(B_IMG * IMGSZ * IMGSZ) / 256, 256, 0, stream>>>(m28, rsz);
  blur_h_kernel<<<(B_IMG * IMGSZ * IMGSZ) / 256, 256, 0, stream>>>(rsz, tmp);
  blur_v_kernel<<<(B_IMG * IMGSZ * IMGSZ) / 256, 256, 0, stream>>>(tmp, out + 8);
}